// Round 1
// baseline (124.315 us; speedup 1.0000x reference)
//
#include <hip/hip_runtime.h>

typedef float  f32x4  __attribute__((ext_vector_type(4)));
typedef short  short8 __attribute__((ext_vector_type(8)));
typedef __bf16 bf16x8 __attribute__((ext_vector_type(8)));

#define DEV static __device__ __forceinline__

DEV f32x4 mfma16(short8 a, short8 b, f32x4 c) {
  return __builtin_amdgcn_mfma_f32_16x16x32_bf16(
      __builtin_bit_cast(bf16x8, a), __builtin_bit_cast(bf16x8, b), c, 0, 0, 0);
}

// split f32 into bf16 hi (truncated) + bf16 lo (RNE of residual): hi+lo ~ f to ~2^-15 rel
DEV void splitf(float f, unsigned short& hi, unsigned short& lo) {
  unsigned u = __builtin_bit_cast(unsigned, f);
  hi = (unsigned short)(u >> 16);
  float hf = __builtin_bit_cast(float, u & 0xFFFF0000u);
  float r = f - hf;
  unsigned v = __builtin_bit_cast(unsigned, r);
  lo = (unsigned short)((v + 0x7FFFu + ((v >> 16) & 1u)) >> 16);
}

#define DDIM 640
#define KCH  20            // 640 / 32 k-chunks for GEMM1
#define MKP_ELEMS (KCH*2*4*64*8)   // 81920 ushorts = 163840 B
#define MVP_OFF   MKP_ELEMS

// Pack Mk (fragment order for GEMM1 B) and Mv^T (fragment order for GEMM2 B) as bf16 hi/lo.
// MkP layout: [c(20)][plane(2)][g(4)][lane(64)][j(8)]  ushort
//   holds Mk[m=16g+(l&15)][d=32c+8*(l>>4)+j]
// MvP layout: [n(40)][c(2)][plane(2)][lane(64)][j(8)]  ushort
//   holds Mv[m=32c+8*(l>>4)+j][d=16n+(l&15)]
__global__ void ea_pack(const float* __restrict__ Mk, const float* __restrict__ Mv,
                        unsigned short* __restrict__ ws) {
  int tid = blockIdx.x * 256 + threadIdx.x;
  unsigned short* MkP = ws;
  unsigned short* MvP = ws + MVP_OFF;
  if (tid < 5120) {                       // 20*4*64 slots
    int c = tid >> 8;
    int g = (tid >> 6) & 3;
    int l = tid & 63;
    int t = l & 15, q = l >> 4;
    const float* src = Mk + (16*g + t) * DDIM + 32*c + 8*q;
    unsigned short* dh = MkP + (((c*2 + 0)*4 + g)*64 + l)*8;
    unsigned short* dl = MkP + (((c*2 + 1)*4 + g)*64 + l)*8;
#pragma unroll
    for (int j = 0; j < 8; ++j) splitf(src[j], dh[j], dl[j]);
  } else if (tid < 10240) {               // 40*2*64 slots
    int s = tid - 5120;
    int n = s >> 7;
    int c = (s >> 6) & 1;
    int l = s & 63;
    int t = l & 15, q = l >> 4;
    const float* src = Mv + (32*c + 8*q) * DDIM + 16*n + t;
    unsigned short* dh = MvP + (((n*2 + c)*2 + 0)*64 + l)*8;
    unsigned short* dl = MvP + (((n*2 + c)*2 + 1)*64 + l)*8;
#pragma unroll
    for (int j = 0; j < 8; ++j) splitf(src[j*DDIM], dh[j], dl[j]);
  }
}

// One block = 64 rows. 4 waves. GEMM1: wave w -> rows 16w..16w+15, all 64 m.
// Softmax in registers (shfl_xor over the 16-lane quarter). W -> LDS (bf16 hi/lo, XOR-swizzled).
// GEMM2: wave w -> n-groups [10w,10w+10), all 64 rows.
__global__ __launch_bounds__(256) void ea_main(const float* __restrict__ x,
                                               const unsigned short* __restrict__ MkP,
                                               const unsigned short* __restrict__ MvP,
                                               float* __restrict__ out) {
  __shared__ unsigned short Wh[64][64];
  __shared__ unsigned short Wl[64][64];
  const int tid = threadIdx.x;
  const int w = tid >> 6;
  const int l = tid & 63;
  const int t = l & 15;
  const int q = l >> 4;
  const long r0 = (long)blockIdx.x * 64;

  // ---------------- GEMM1: scores ----------------
  const float* xp = x + (r0 + 16*w + t) * DDIM + 8*q;
  f32x4 acc[4];
#pragma unroll
  for (int g = 0; g < 4; ++g) acc[g] = (f32x4){0.f, 0.f, 0.f, 0.f};

#pragma unroll 2
  for (int c = 0; c < KCH; ++c) {
    f32x4 xa = *(const f32x4*)(xp + 32*c);
    f32x4 xb = *(const f32x4*)(xp + 32*c + 4);
    union { short8 s; unsigned short u[8]; } ah, al;
#pragma unroll
    for (int i = 0; i < 4; ++i) {
      splitf(xa[i], ah.u[i],     al.u[i]);
      splitf(xb[i], ah.u[4 + i], al.u[4 + i]);
    }
    const unsigned short* mkc = MkP + c * 4096;
    short8 bh[4], bl[4];
#pragma unroll
    for (int g = 0; g < 4; ++g) {
      bh[g] = *(const short8*)(mkc +        (g*64 + l)*8);
      bl[g] = *(const short8*)(mkc + 2048 + (g*64 + l)*8);
    }
#pragma unroll
    for (int g = 0; g < 4; ++g) {
      acc[g] = mfma16(ah.s, bh[g], acc[g]);
      acc[g] = mfma16(al.s, bh[g], acc[g]);
      acc[g] = mfma16(ah.s, bl[g], acc[g]);
    }
  }

  // ---------------- softmax over m (64) per row ----------------
  // lane holds S[row = 4q+j (local to wave)][m = 16g+t], g=0..3, j=0..3
  float rmax[4], rsum[4];
#pragma unroll
  for (int j = 0; j < 4; ++j)
    rmax[j] = fmaxf(fmaxf(acc[0][j], acc[1][j]), fmaxf(acc[2][j], acc[3][j]));
#pragma unroll
  for (int mk = 1; mk <= 8; mk <<= 1) {
#pragma unroll
    for (int j = 0; j < 4; ++j)
      rmax[j] = fmaxf(rmax[j], __shfl_xor(rmax[j], mk, 64));
  }
  float p[4][4];
#pragma unroll
  for (int g = 0; g < 4; ++g) {
#pragma unroll
    for (int j = 0; j < 4; ++j)
      p[g][j] = exp2f((acc[g][j] - rmax[j]) * 1.44269504f);
  }
#pragma unroll
  for (int j = 0; j < 4; ++j)
    rsum[j] = (p[0][j] + p[1][j]) + (p[2][j] + p[3][j]);
#pragma unroll
  for (int mk = 1; mk <= 8; mk <<= 1) {
#pragma unroll
    for (int j = 0; j < 4; ++j)
      rsum[j] += __shfl_xor(rsum[j], mk, 64);
  }
  float rinv[4];
#pragma unroll
  for (int j = 0; j < 4; ++j) rinv[j] = 1.0f / rsum[j];

#pragma unroll
  for (int g = 0; g < 4; ++g) {
#pragma unroll
    for (int j = 0; j < 4; ++j) {
      float wt = p[g][j] * rinv[j];
      unsigned short hi, lo;
      splitf(wt, hi, lo);
      int row = 16*w + 4*q + j;
      int ms  = (16*g + t) ^ ((row & 7) << 3);   // XOR swizzle, 8-ushort granules
      Wh[row][ms] = hi;
      Wl[row][ms] = lo;
    }
  }
  __syncthreads();

  // ---------------- GEMM2: out = W @ Mv ----------------
  const int n0 = w * 10;
#pragma unroll 1
  for (int n = n0; n < n0 + 10; ++n) {
    const unsigned short* mvp = MvP + n * 2048;
    short8 vh[2], vl[2];
#pragma unroll
    for (int c = 0; c < 2; ++c) {
      vh[c] = *(const short8*)(mvp + ((c*2 + 0)*64 + l)*8);
      vl[c] = *(const short8*)(mvp + ((c*2 + 1)*64 + l)*8);
    }
#pragma unroll
    for (int rg = 0; rg < 4; ++rg) {
      f32x4 o = (f32x4){0.f, 0.f, 0.f, 0.f};
      const int arow = 16*rg + t;
      const int sw   = (arow & 7) << 3;
#pragma unroll
      for (int c = 0; c < 2; ++c) {
        const int ms = (32*c + 8*q) ^ sw;
        short8 aH = *(const short8*)&Wh[arow][ms];
        short8 aL = *(const short8*)&Wl[arow][ms];
        o = mfma16(aH, vh[c], o);
        o = mfma16(aL, vh[c], o);
        o = mfma16(aH, vl[c], o);
      }
      float* op = out + (r0 + 16*rg + 4*q) * DDIM + 16*n + t;
#pragma unroll
      for (int j = 0; j < 4; ++j) op[j * DDIM] = o[j];
    }
  }
}

extern "C" void kernel_launch(void* const* d_in, const int* in_sizes, int n_in,
                              void* d_out, int out_size, void* d_ws, size_t ws_size,
                              hipStream_t stream) {
  const float* x  = (const float*)d_in[0];
  const float* Mk = (const float*)d_in[1];
  const float* Mv = (const float*)d_in[2];
  float* outp = (float*)d_out;
  unsigned short* ws = (unsigned short*)d_ws;

  ea_pack<<<40, 256, 0, stream>>>(Mk, Mv, ws);
  ea_main<<<1024, 256, 0, stream>>>(x, ws, ws + MVP_OFF, outp);
}